// Round 14
// baseline (1883.835 us; speedup 1.0000x reference)
//
#include <hip/hip_runtime.h>
#include <cstdint>
#include <cstddef>

typedef _Float16 half_t;
typedef _Float16 h8 __attribute__((ext_vector_type(8)));
typedef _Float16 h4 __attribute__((ext_vector_type(4)));
typedef float f32x4 __attribute__((ext_vector_type(4)));

#define BATCHN 128
#define HWN    225

__device__ __forceinline__ float swishf(float x){ return x / (1.f + __expf(-x)); }

__device__ __forceinline__ void diroff(int d, int o, int& dh, int& dw){
  if (d == 0)      { dh = 0;  dw = o; }
  else if (d == 1) { dh = o;  dw = 0; }
  else if (d == 2) { dh = o;  dw = o; }
  else             { dh = -o; dw = o; }
}

// ---------------- weight conversion fp32 -> fp16 ----------------
__global__ void k_wconv(const float* __restrict__ rbw, const float* __restrict__ rbw2,
                        const float* __restrict__ trw1, const float* __restrict__ trw2,
                        const float* __restrict__ fcw,
                        half_t* __restrict__ W1L, half_t* __restrict__ W2,
                        half_t* __restrict__ TW1, half_t* __restrict__ TW2,
                        half_t* __restrict__ FCW)
{
  int e = blockIdx.x * 256 + threadIdx.x;
  if (e < 786432) {
    int j = e / 196608; int r = e - j * 196608;
    int oc = r / 768;   int k = r - oc * 768;
    int t = k >> 8;     int ic = k & 255;
    W1L[e] = (half_t)rbw[(((size_t)(j*3 + t) * 256 + oc) * 256) + ic];
    return;
  }
  int e2 = e - 786432;
  if (e2 < 262144) { W2[e2] = (half_t)rbw2[e2]; return; }
  int e3 = e2 - 262144;
  if (e3 < 327680) { TW1[e3] = (half_t)trw1[e3]; return; }
  int e4 = e3 - 327680;
  if (e4 < 327680) { TW2[e4] = (half_t)trw2[e4]; return; }
  int e5 = e4 - 327680;
  if (e5 < 32768)  { FCW[e5] = (half_t)fcw[e5]; }
}

// ---------------- fused residual pair: quarter-tiled, 2m x 4n, copy-free ping-pong ----------------
// 512 threads = 8 waves (2m x 4n): wave tile 32 rows x 64 cols; acc[2][4]=32 VGPR.
// M in 4 sequential 64-row quarters. GEMM1 barrier-free (B from L2-hot global).
// Ping-pong prefetch: group parity == ks, so ks bodies are explicit with two
// static register sets (no copies). Runtime kc/kt2 loops stay unroll 1.
// ylds: 226x256 fp16, row stride 512B, byte ^= ((row&7)<<4). stg: 64x256 fp16.
template<bool LINE>
__device__ __forceinline__ void run_pair(half_t* ylds, half_t* stg,
                                         const half_t* __restrict__ W1p,
                                         const float* __restrict__ b1p,
                                         const half_t* __restrict__ W2p,
                                         const float* __restrict__ b2p,
                                         int d, int wm, int wn, int l15, int lq)
{
  constexpr int TAPS = LINE ? 3 : 1;
  constexpr int K1   = LINE ? 768 : 256;

  __syncthreads();   // entry: ylds stable

  float b1v[4], b2v[4];
  #pragma unroll
  for (int nt = 0; nt < 4; ++nt) {
    int col = wn*64 + nt*16 + l15;
    b1v[nt] = b1p[col]; b2v[nt] = b2p[col];
  }
  const half_t* w1r[4];
  const half_t* w2r[4];
  #pragma unroll
  for (int nt = 0; nt < 4; ++nt) {
    int row = wn*64 + nt*16 + l15;
    w1r[nt] = W1p + (size_t)row*K1  + lq*8;
    w2r[nt] = W2p + (size_t)row*256 + lq*8;
  }

  h4 dprev[2][4];   // parked delta of previous quarter (LINE only)

  #pragma unroll 1
  for (int q = 0; q < 4; ++q) {
    // gather row byte-offsets + XOR keys for this quarter
    int qb[2][TAPS], qx[2][TAPS];
    #pragma unroll
    for (int mt = 0; mt < 2; ++mt) {
      int p = q*64 + wm*32 + mt*16 + l15;
      int pc = (p < 225) ? p : 225;
      if (LINE) {
        int h = pc / 15, w = pc - 15*(pc/15);
        #pragma unroll
        for (int t = 0; t < 3; ++t) {
          int dh, dw; diroff(d, t - 1, dh, dw);
          int h2 = h + dh, w2 = w + dw;
          int qq = (pc < 225 && (unsigned)h2 < 15u && (unsigned)w2 < 15u) ? (h2*15 + w2) : 225;
          qb[mt][t] = qq * 512;
          qx[mt][t] = (qq & 7) << 4;
        }
      } else {
        qb[mt][0] = pc * 512;
        qx[mt][0] = (pc & 7) << 4;
      }
    }

    f32x4 acc[2][4];
    #pragma unroll
    for (int a = 0; a < 2; ++a)
      #pragma unroll
      for (int b = 0; b < 4; ++b) { f32x4 z = {0.f,0.f,0.f,0.f}; acc[a][b] = z; }

    // ---- GEMM1: copy-free ping-pong (buf0 = ks0, buf1 = ks1) ----
    h8 a0[2], b0[4], a1[2], b1f[4];
    {
      const int cb = lq*16;
      #pragma unroll
      for (int mt = 0; mt < 2; ++mt)
        a0[mt] = *(const h8*)((const char*)ylds + qb[mt][0] + (cb ^ qx[mt][0]));
      #pragma unroll
      for (int nt = 0; nt < 4; ++nt)
        b0[nt] = *(const h8*)(w1r[nt]);
    }
    #pragma unroll
    for (int tap = 0; tap < TAPS; ++tap) {
      #pragma unroll 1
      for (int kc = 0; kc < 4; ++kc) {
        // ks=0: prefetch (tap,kc,1) into buf1, MFMA buf0
        {
          int cb = kc*128 + 64 + lq*16;
          #pragma unroll
          for (int mt = 0; mt < 2; ++mt)
            a1[mt] = *(const h8*)((const char*)ylds + qb[mt][tap] + (cb ^ qx[mt][tap]));
          int ko = (tap*4 + kc)*64 + 32;
          #pragma unroll
          for (int nt = 0; nt < 4; ++nt)
            b1f[nt] = *(const h8*)(w1r[nt] + ko);
          #pragma unroll
          for (int nt = 0; nt < 4; ++nt)
            #pragma unroll
            for (int mt = 0; mt < 2; ++mt)
              acc[mt][nt] = __builtin_amdgcn_mfma_f32_16x16x32_f16(a0[mt], b0[nt], acc[mt][nt], 0, 0, 0);
        }
        // ks=1: prefetch next group into buf0 (if any), MFMA buf1
        {
          int tapn = (tap + 1 < TAPS) ? tap + 1 : tap;   // folds after tap-unroll
          if (kc < 3) {
            int cb = (kc + 1)*128 + lq*16;
            #pragma unroll
            for (int mt = 0; mt < 2; ++mt)
              a0[mt] = *(const h8*)((const char*)ylds + qb[mt][tap] + (cb ^ qx[mt][tap]));
            int ko = (tap*4 + kc + 1)*64;
            #pragma unroll
            for (int nt = 0; nt < 4; ++nt)
              b0[nt] = *(const h8*)(w1r[nt] + ko);
          } else if (tap + 1 < TAPS) {
            int cb = lq*16;
            #pragma unroll
            for (int mt = 0; mt < 2; ++mt)
              a0[mt] = *(const h8*)((const char*)ylds + qb[mt][tapn] + (cb ^ qx[mt][tapn]));
            int ko = (tap + 1)*256;
            #pragma unroll
            for (int nt = 0; nt < 4; ++nt)
              b0[nt] = *(const h8*)(w1r[nt] + ko);
          }
          #pragma unroll
          for (int nt = 0; nt < 4; ++nt)
            #pragma unroll
            for (int mt = 0; mt < 2; ++mt)
              acc[mt][nt] = __builtin_amdgcn_mfma_f32_16x16x32_f16(a1[mt], b1f[nt], acc[mt][nt], 0, 0, 0);
        }
      }
    }

    // swish1 -> packed fp16
    h4 s1h[2][4];
    #pragma unroll
    for (int mt = 0; mt < 2; ++mt)
      #pragma unroll
      for (int nt = 0; nt < 4; ++nt)
        #pragma unroll
        for (int r = 0; r < 4; ++r)
          s1h[mt][nt][r] = (half_t)swishf(acc[mt][nt][r] + b1v[nt]);

    __syncthreads();   // A: all GEMM1 gathers of this quarter done; stg reusable

    // apply previous quarter's parked delta (LINE)
    if (LINE && q >= 1) {
      #pragma unroll
      for (int mt = 0; mt < 2; ++mt)
        #pragma unroll
        for (int nt = 0; nt < 4; ++nt)
          #pragma unroll
          for (int r = 0; r < 4; ++r) {
            int p = (q-1)*64 + wm*32 + mt*16 + lq*4 + r;
            if (p < 225) {
              int c = wn*64 + nt*16 + l15;
              half_t* ad = (half_t*)((char*)ylds + p*512 + ((c*2) ^ ((p & 7) << 4)));
              *ad = (half_t)((float)*ad + (float)dprev[mt][nt][r]);
            }
          }
    }

    // stage s1 (64 x 256) into stg
    #pragma unroll
    for (int mt = 0; mt < 2; ++mt)
      #pragma unroll
      for (int nt = 0; nt < 4; ++nt)
        #pragma unroll
        for (int r = 0; r < 4; ++r) {
          int lr = wm*32 + mt*16 + lq*4 + r;
          int cc = wn*64 + nt*16 + l15;
          *(half_t*)((char*)stg + lr*512 + ((cc*2) ^ ((lr & 7) << 4))) = s1h[mt][nt][r];
        }
    __syncthreads();   // B: s1 staged (also fences dprev writes before next gathers)

    // ---- GEMM2: acc = s1 x W2^T; same ping-pong; A from stg, B global ----
    #pragma unroll
    for (int a = 0; a < 2; ++a)
      #pragma unroll
      for (int b = 0; b < 4; ++b) { f32x4 z = {0.f,0.f,0.f,0.f}; acc[a][b] = z; }

    int sb[2], sx[2];
    #pragma unroll
    for (int mt = 0; mt < 2; ++mt) {
      int lr = wm*32 + mt*16 + l15;
      sb[mt] = lr*512; sx[mt] = (lr & 7) << 4;
    }
    {
      const int cb = lq*16;
      #pragma unroll
      for (int mt = 0; mt < 2; ++mt)
        a0[mt] = *(const h8*)((const char*)stg + sb[mt] + (cb ^ sx[mt]));
      #pragma unroll
      for (int nt = 0; nt < 4; ++nt)
        b0[nt] = *(const h8*)(w2r[nt]);
    }
    #pragma unroll 1
    for (int kt2 = 0; kt2 < 4; ++kt2) {
      // ks=0: prefetch (kt2,1) into buf1, MFMA buf0
      {
        int cb = kt2*128 + 64 + lq*16;
        #pragma unroll
        for (int mt = 0; mt < 2; ++mt)
          a1[mt] = *(const h8*)((const char*)stg + sb[mt] + (cb ^ sx[mt]));
        int ko = kt2*64 + 32;
        #pragma unroll
        for (int nt = 0; nt < 4; ++nt)
          b1f[nt] = *(const h8*)(w2r[nt] + ko);
        #pragma unroll
        for (int nt = 0; nt < 4; ++nt)
          #pragma unroll
          for (int mt = 0; mt < 2; ++mt)
            acc[mt][nt] = __builtin_amdgcn_mfma_f32_16x16x32_f16(a0[mt], b0[nt], acc[mt][nt], 0, 0, 0);
      }
      // ks=1: prefetch (kt2+1,0) into buf0 (if any), MFMA buf1
      {
        if (kt2 < 3) {
          int cb = (kt2 + 1)*128 + lq*16;
          #pragma unroll
          for (int mt = 0; mt < 2; ++mt)
            a0[mt] = *(const h8*)((const char*)stg + sb[mt] + (cb ^ sx[mt]));
          int ko = (kt2 + 1)*64;
          #pragma unroll
          for (int nt = 0; nt < 4; ++nt)
            b0[nt] = *(const h8*)(w2r[nt] + ko);
        }
        #pragma unroll
        for (int nt = 0; nt < 4; ++nt)
          #pragma unroll
          for (int mt = 0; mt < 2; ++mt)
            acc[mt][nt] = __builtin_amdgcn_mfma_f32_16x16x32_f16(a1[mt], b1f[nt], acc[mt][nt], 0, 0, 0);
      }
    }

    // ---- epilogue ----
    if (!LINE) {
      #pragma unroll
      for (int mt = 0; mt < 2; ++mt)
        #pragma unroll
        for (int nt = 0; nt < 4; ++nt)
          #pragma unroll
          for (int r = 0; r < 4; ++r) {
            int p = q*64 + wm*32 + mt*16 + lq*4 + r;
            if (p < 225) {
              int c = wn*64 + nt*16 + l15;
              half_t* ad = (half_t*)((char*)ylds + p*512 + ((c*2) ^ ((p & 7) << 4)));
              *ad = (half_t)((float)*ad + swishf(acc[mt][nt][r] + b2v[nt]));
            }
          }
    } else if (q < 3) {
      #pragma unroll
      for (int mt = 0; mt < 2; ++mt)
        #pragma unroll
        for (int nt = 0; nt < 4; ++nt)
          #pragma unroll
          for (int r = 0; r < 4; ++r)
            dprev[mt][nt][r] = (half_t)swishf(acc[mt][nt][r] + b2v[nt]);
    } else {
      #pragma unroll
      for (int mt = 0; mt < 2; ++mt)
        #pragma unroll
        for (int nt = 0; nt < 4; ++nt)
          #pragma unroll
          for (int r = 0; r < 4; ++r) {
            int p = q*64 + wm*32 + mt*16 + lq*4 + r;
            if (p < 225) {
              int c = wn*64 + nt*16 + l15;
              half_t* ad = (half_t*)((char*)ylds + p*512 + ((c*2) ^ ((p & 7) << 4)));
              *ad = (half_t)((float)*ad + swishf(acc[mt][nt][r] + b2v[nt]));
            }
          }
    }
  } // q
}

// ---------------- plane-resident trunk ----------------
// One block per (direction d, image b); 512 threads = 8 waves (2m x 4n).
__launch_bounds__(512, 2)
__global__ void k_trunk(const float* __restrict__ x,
                        const float* __restrict__ fw, const float* __restrict__ fb,
                        const half_t* __restrict__ W1L, const float* __restrict__ rbb,
                        const half_t* __restrict__ W2g, const float* __restrict__ rbb2,
                        const half_t* __restrict__ TW1, const float* __restrict__ trb1,
                        const half_t* __restrict__ TW2, const float* __restrict__ trb2,
                        const half_t* __restrict__ FCW, const float* __restrict__ fcb,
                        float* __restrict__ mapf)
{
  __shared__ __align__(16) half_t ylds[226*256];   // 115,712 B
  __shared__ __align__(16) half_t stg[64*256];     //  32,768 B
  const int tid = threadIdx.x;
  const int lane = tid & 63;
  const int wv = tid >> 6;                          // 0..7
  const int wm = wv >> 2, wn = wv & 3;              // 2m x 4n
  const int l15 = lane & 15, lq = lane >> 4;
  const int pid = blockIdx.x;
  const int d = pid >> 7, bimg = pid & 127;

  // ---- first layer: y = swish(line_conv3(x)) into ylds ----
  {
    float* xl = (float*)stg;                        // 450 floats
    if (tid < 450) xl[tid] = x[(size_t)bimg*450 + tid];
    __syncthreads();
    const int c = tid & 255;
    float fwv0[3], fwv1[3];
    #pragma unroll
    for (int t = 0; t < 3; ++t) {
      fwv0[t] = fw[(t*256 + c)*2 + 0];
      fwv1[t] = fw[(t*256 + c)*2 + 1];
    }
    float fbv = fb[c];
    for (int e = tid; e < 226*256; e += 512) {
      int p = e >> 8;
      float v = 0.f;
      if (p < 225) {
        int h = p / 15, w = p - 15*(p/15);
        float a = fbv;
        #pragma unroll
        for (int t = 0; t < 3; ++t) {
          int dh, dw; diroff(d, t - 1, dh, dw);
          int h2 = h + dh, w2 = w + dw;
          if ((unsigned)h2 < 15u && (unsigned)w2 < 15u)
            a += fwv0[t]*xl[h2*15+w2] + fwv1[t]*xl[225 + h2*15+w2];
        }
        v = swishf(a);
      }
      *(half_t*)((char*)ylds + p*512 + (((e & 255)*2) ^ ((p & 7) << 4))) = (half_t)v;
    }
  }

  // ---- 9 residual pairs ----
  #pragma unroll 1
  for (int j = 0; j < 4; ++j)
    run_pair<true>(ylds, stg, W1L + (size_t)j*196608, rbb + j*256,
                   W2g + (size_t)j*65536, rbb2 + j*256, d, wm, wn, l15, lq);
  #pragma unroll 1
  for (int j = 0; j < 5; ++j)
    run_pair<false>(ylds, stg, TW1 + (size_t)j*65536, trb1 + j*256,
                    TW2 + (size_t)j*65536, trb2 + j*256, d, wm, wn, l15, lq);

  // ---- fc GEMM: mapf = 30*tanh((y x FCW^T + b)/30); wave wv -> cols wv*16..+15 ----
  {
    __syncthreads();   // last epilogue done
    float fbv2 = fcb[wv*16 + l15];
    #pragma unroll 1
    for (int q = 0; q < 4; ++q) {
      int qb0[4];
      #pragma unroll
      for (int mt = 0; mt < 4; ++mt) {
        int p = q*64 + mt*16 + l15;
        qb0[mt] = ((p < 225) ? p : 225) * 512;
      }
      f32x4 acc[4];
      #pragma unroll
      for (int a = 0; a < 4; ++a) { f32x4 z = {0.f,0.f,0.f,0.f}; acc[a] = z; }

      #pragma unroll 1
      for (int kt = 0; kt < 4; ++kt) {
        #pragma unroll
        for (int ks = 0; ks < 2; ++ks) {
          h8 af[4];
          #pragma unroll
          for (int mt = 0; mt < 4; ++mt) {
            int cb = kt*128 + ks*64 + lq*16;
            af[mt] = *(const h8*)((const char*)ylds + qb0[mt] + (cb ^ ((qb0[mt] >> 5) & 0x70)));
          }
          int row = wv*16 + l15;
          h8 bf = *(const h8*)(FCW + (size_t)row*256 + kt*64 + ks*32 + lq*8);
          #pragma unroll
          for (int mt = 0; mt < 4; ++mt)
            acc[mt] = __builtin_amdgcn_mfma_f32_16x16x32_f16(af[mt], bf, acc[mt], 0, 0, 0);
        }
      }
      #pragma unroll
      for (int mt = 0; mt < 4; ++mt)
        #pragma unroll
        for (int r = 0; r < 4; ++r) {
          int p = q*64 + mt*16 + lq*4 + r;
          if (p < 225) {
            int col = wv*16 + l15;
            float v = acc[mt][r] + fbv2;
            mapf[((size_t)((d*BATCHN + bimg)*225 + p))*128 + col] = 30.f * tanhf(v * (1.f/30.f));
          }
        }
    }
  }
}

// ---------------- h1 = prelu(mean_d g1, g1lr_s, bound .999) ----------------
__global__ void k_h1(const float* __restrict__ mapf, const float* __restrict__ g1s,
                     float* __restrict__ h1)
{
  __shared__ float accs[225*65];
  int b = blockIdx.x, tid = threadIdx.x;
  for (int d = 0; d < 4; ++d) {
    for (int e = tid; e < 225*64; e += 256) {
      int hw = e >> 6, c = e & 63;
      float v = mapf[((size_t)(d*BATCHN + b)*225 + hw)*128 + c];
      if (d == 0) accs[hw*65 + c] = v; else accs[hw*65 + c] += v;
    }
  }
  __syncthreads();
  for (int e = tid; e < 225*64; e += 256) {
    int c = e / 225, hw = e - c*225;
    float s = tanhf(g1s[c] * (1.f/0.999f)) * 0.999f;
    float v = accs[hw*65 + c] * 0.25f;
    h1[((size_t)b*64 + c)*225 + hw] = fmaxf(v, s*v);
  }
}

// ---------------- h1c(avg sym) -> h2 -> h3 -> trunk0 ----------------
__global__ void k_h2(const float* __restrict__ h1, const float* __restrict__ mapf,
                     const float* __restrict__ h1w, const float* __restrict__ h1b,
                     const float* __restrict__ s1p, const float* __restrict__ s2p,
                     const float* __restrict__ s3p, const float* __restrict__ b3p,
                     float* __restrict__ tr0)
{
  int bc = blockIdx.x; int b = bc >> 6; int c = bc & 63;
  __shared__ float pl[225];
  int tid = threadIdx.x;
  if (tid < 225) pl[tid] = h1[((size_t)b*64 + c)*225 + tid];
  __syncthreads();
  if (tid >= 225) return;
  int h = tid / 15, w = tid - (tid/15)*15;
  float wk[11];
  #pragma unroll
  for (int i = 0; i < 11; ++i) wk[i] = h1w[i*64 + c];
  float bias = h1b[c];
  float sl1 = tanhf(s1p[c] * (1.f/0.999f)) * 0.999f;
  float sl2 = tanhf(s2p[c] * (1.f/0.999f)) * 0.999f;
  float tsum = 0.f;
  for (int d = 0; d < 4; ++d) {
    float hc = bias;
    #pragma unroll
    for (int i = 0; i < 11; ++i) {
      int dh, dw; diroff(d, i - 5, dh, dw);
      int hp = h + dh, wp = w + dw;
      float vp = ((unsigned)hp < 15u && (unsigned)wp < 15u) ? pl[hp*15 + wp] : 0.f;
      int hm = h - dh, wm = w - dw;
      float vm = ((unsigned)hm < 15u && (unsigned)wm < 15u) ? pl[hm*15 + wm] : 0.f;
      hc += 0.5f * wk[i] * (vp + vm);
    }
    float t = fmaxf(hc, sl1*hc);
    t += mapf[((size_t)(d*BATCHN + b)*225 + tid)*128 + 64 + c];
    t = fmaxf(t, sl2*t);
    tsum += t;
  }
  float h3v = tsum * 0.25f + b3p[c];
  float sl3 = tanhf(s3p[c] * (1.f/0.999f)) * 0.999f;
  tr0[((size_t)b*64 + c)*225 + tid] = fmaxf(h3v, sl3*h3v);
}

// ---------------- shuffle -> grouped 1x1 -> shuffle -> prelu ----------------
__global__ void k_head1(const float* __restrict__ tr0, const float* __restrict__ tc1w,
                        const float* __restrict__ tc1b, const float* __restrict__ tlr1,
                        float* __restrict__ t1o)
{
  __shared__ float st[64*228];
  int b = blockIdx.x, tid = threadIdx.x;
  for (int e = tid; e < 64*225; e += 256) {
    int c = e / 225, hw = e - c*225;
    st[c*228 + hw] = tr0[((size_t)b*64 + c)*225 + hw];
  }
  __syncthreads();
  float s2v[64];
  if (tid < 225) {
    #pragma unroll
    for (int g = 0; g < 16; ++g) {
      int gg = g >> 2, rr = g & 3;
      float x0 = st[(gg*16 + 0*4 + rr)*228 + tid];
      float x1 = st[(gg*16 + 1*4 + rr)*228 + tid];
      float x2 = st[(gg*16 + 2*4 + rr)*228 + tid];
      float x3 = st[(gg*16 + 3*4 + rr)*228 + tid];
      #pragma unroll
      for (int o = 0; o < 4; ++o) {
        s2v[g*4 + o] = tc1b[g*4 + o]
          + x0*tc1w[(g*4 + o)*4 + 0] + x1*tc1w[(g*4 + o)*4 + 1]
          + x2*tc1w[(g*4 + o)*4 + 2] + x3*tc1w[(g*4 + o)*4 + 3];
      }
    }
  }
  __syncthreads();
  if (tid < 225) {
    #pragma unroll
    for (int c = 0; c < 64; ++c) {
      int gg = c >> 4, q = c & 15, ii = q >> 2, jj = q & 3;
      float v = s2v[gg*16 + jj*4 + ii];
      float sl = tanhf(tlr1[c] * (1.f/0.999f)) * 0.999f;
      st[c*228 + tid] = fmaxf(v, sl*v);
    }
  }
  __syncthreads();
  for (int e = tid; e < 64*225; e += 256) {
    int c = e / 225, hw = e - c*225;
    t1o[((size_t)b*64 + c)*225 + hw] = st[c*228 + hw];
  }
}

// ---------------- sym3 depthwise conv + policy head + value pre-pool ----------------
__global__ void k_head2(const float* __restrict__ t1, const float* __restrict__ tc2w,
                        const float* __restrict__ t2ps, const float* __restrict__ t2pb,
                        const float* __restrict__ t2vs, const float* __restrict__ t2vb,
                        const float* __restrict__ polw,
                        float* __restrict__ pout, float* __restrict__ vpre)
{
  __shared__ float st[64*228];
  __shared__ float vbuf[64*228];
  __shared__ float psum[64*4];
  int b = blockIdx.x, tid = threadIdx.x;
  for (int e = tid; e < 64*225; e += 256) {
    int c = e / 225, hw = e - c*225;
    st[c*228 + hw] = t1[((size_t)b*64 + c)*225 + hw];
  }
  __syncthreads();
  if (tid < 225) {
    int h = tid / 15, w = tid - (tid/15)*15;
    float pacc = 0.f;
    for (int c = 0; c < 64; ++c) {
      const float* pc = &st[c*228];
      float ctr = pc[tid];
      float up = (h > 0)  ? pc[tid - 15] : 0.f;
      float dn = (h < 14) ? pc[tid + 15] : 0.f;
      float lf = (w > 0)  ? pc[tid - 1]  : 0.f;
      float rt = (w < 14) ? pc[tid + 1]  : 0.f;
      float ul = (h > 0  && w > 0)  ? pc[tid - 16] : 0.f;
      float ur = (h > 0  && w < 14) ? pc[tid - 14] : 0.f;
      float dl = (h < 14 && w > 0)  ? pc[tid + 14] : 0.f;
      float dr = (h < 14 && w < 14) ? pc[tid + 16] : 0.f;
      float s3 = tc2w[c]*ctr + tc2w[64 + c]*(up + dn + lf + rt)
               + tc2w[128 + c]*(ul + ur + dl + dr);
      float yp = s3 + t2pb[c];
      float sp = tanhf(t2ps[c] * (1.f/0.999f)) * 0.999f;
      pacc += fmaxf(yp, sp*yp) * polw[c];
      float yv = s3 + t2vb[c];
      float sv = tanhf(t2vs[c] * (1.f/0.999f)) * 0.999f;
      vbuf[c*228 + tid] = fmaxf(yv, sv*yv);
    }
    pout[(size_t)b*225 + tid] = pacc;
  }
  __syncthreads();
  {
    int c = tid & 63, q = tid >> 6;
    int h0 = q * 57; int h1e = (h0 + 57 < 225) ? h0 + 57 : 225;
    float s = 0.f;
    for (int hw = h0; hw < h1e; ++hw) s += vbuf[c*228 + hw];
    psum[c*4 + q] = s;
  }
  __syncthreads();
  if (tid < 64) {
    float s = (psum[tid*4] + psum[tid*4+1] + psum[tid*4+2] + psum[tid*4+3]) * (1.f/225.f);
    vpre[(size_t)b*64 + tid] = s;
  }
}

// ---------------- value MLP ----------------
__global__ void k_mlp(const float* __restrict__ vpre, const float* __restrict__ vls,
                      const float* __restrict__ vlb,
                      const float* __restrict__ w1, const float* __restrict__ b1,
                      const float* __restrict__ w2, const float* __restrict__ b2,
                      const float* __restrict__ w3, const float* __restrict__ b3,
                      const float* __restrict__ wf, const float* __restrict__ bfv,
                      float* __restrict__ vout)
{
  __shared__ float va[64], vb2[64];
  int b = blockIdx.x, t = threadIdx.x;
  float x = vpre[(size_t)b*64 + t];
  float s = tanhf(vls[t] * 0.1f) * 10.f;
  float y = x + vlb[t];
  va[t] = fmaxf(y, s*y);
  __syncthreads();
  float acc = b1[t];
  for (int i = 0; i < 64; ++i) acc += w1[t*64 + i] * va[i];
  vb2[t] = fmaxf(acc, 0.f);
  __syncthreads();
  acc = b2[t];
  for (int i = 0; i < 64; ++i) acc += w2[t*64 + i] * vb2[i];
  va[t] = fmaxf(acc, 0.f);
  __syncthreads();
  acc = b3[t];
  for (int i = 0; i < 64; ++i) acc += w3[t*64 + i] * va[i];
  vb2[t] = fmaxf(acc, 0.f);
  __syncthreads();
  if (t < 3) {
    float o = bfv[t];
    for (int i = 0; i < 64; ++i) o += wf[t*64 + i] * vb2[i];
    vout[(size_t)b*3 + t] = o;
  }
}

extern "C" void kernel_launch(void* const* d_in, const int* in_sizes, int n_in,
                              void* d_out, int out_size, void* d_ws, size_t ws_size,
                              hipStream_t stream)
{
  (void)in_sizes; (void)n_in; (void)out_size; (void)ws_size;
  const float* x     = (const float*)d_in[0];
  const float* fw    = (const float*)d_in[1];
  const float* fb    = (const float*)d_in[2];
  const float* rb_w  = (const float*)d_in[3];
  const float* rb_b  = (const float*)d_in[4];
  const float* rb_w2 = (const float*)d_in[5];
  const float* rb_b2 = (const float*)d_in[6];
  const float* tr_w1 = (const float*)d_in[7];
  const float* tr_b1 = (const float*)d_in[8];
  const float* tr_w2 = (const float*)d_in[9];
  const float* tr_b2 = (const float*)d_in[10];
  const float* fc_w  = (const float*)d_in[11];
  const float* fc_b  = (const float*)d_in[12];
  const float* g1lr  = (const float*)d_in[13];
  const float* h1w   = (const float*)d_in[14];
  const float* h1b   = (const float*)d_in[15];
  const float* h1lr1 = (const float*)d_in[16];
  const float* h1lr2 = (const float*)d_in[17];
  const float* h3lr  = (const float*)d_in[18];
  const float* h3lb  = (const float*)d_in[19];
  const float* tc1w  = (const float*)d_in[20];
  const float* tc1b  = (const float*)d_in[21];
  const float* tlr1  = (const float*)d_in[22];
  const float* tc2w  = (const float*)d_in[23];
  const float* t2ps  = (const float*)d_in[24];
  const float* t2pb  = (const float*)d_in[25];
  const float* t2vs  = (const float*)d_in[26];
  const float* t2vb  = (const float*)d_in[27];
  const float* polw  = (const float*)d_in[28];
  const float* vls   = (const float*)d_in[29];
  const float* vlb   = (const float*)d_in[30];
  const float* v1w   = (const float*)d_in[31];
  const float* v1b   = (const float*)d_in[32];
  const float* v2w   = (const float*)d_in[33];
  const float* v2b   = (const float*)d_in[34];
  const float* v3w   = (const float*)d_in[35];
  const float* v3b   = (const float*)d_in[36];
  const float* vfw   = (const float*)d_in[37];
  const float* vfb   = (const float*)d_in[38];

  char* ws = (char*)d_ws;
  size_t off = 0;
  auto alloc = [&](size_t bytes) -> void* {
    void* p = ws + off;
    off += (bytes + 255) & ~(size_t)255;
    return p;
  };
  float* MAPF = (float*)alloc((size_t)4*BATCHN*225*128*4);   // 59 MB
  float* H1   = (float*)alloc((size_t)BATCHN*64*225*4);
  float* TR0  = (float*)alloc((size_t)BATCHN*64*225*4);
  float* T1B  = (float*)alloc((size_t)BATCHN*64*225*4);
  float* VPRE = (float*)alloc((size_t)BATCHN*64*4);
  half_t* W1L = (half_t*)alloc((size_t)4*256*768*2);
  half_t* W2  = (half_t*)alloc((size_t)4*256*256*2);
  half_t* TW1 = (half_t*)alloc((size_t)5*256*256*2);
  half_t* TW2 = (half_t*)alloc((size_t)5*256*256*2);
  half_t* FCW = (half_t*)alloc((size_t)128*256*2);

  k_wconv<<<6784, 256, 0, stream>>>(rb_w, rb_w2, tr_w1, tr_w2, fc_w, W1L, W2, TW1, TW2, FCW);
  k_trunk<<<512, 512, 0, stream>>>(x, fw, fb, W1L, rb_b, W2, rb_b2,
                                   TW1, tr_b1, TW2, tr_b2, FCW, fc_b, MAPF);

  k_h1<<<128, 256, 0, stream>>>(MAPF, g1lr, H1);
  k_h2<<<8192, 256, 0, stream>>>(H1, MAPF, h1w, h1b, h1lr1, h1lr2, h3lr, h3lb, TR0);
  k_head1<<<128, 256, 0, stream>>>(TR0, tc1w, tc1b, tlr1, T1B);
  float* dout = (float*)d_out;
  k_head2<<<128, 256, 0, stream>>>(T1B, tc2w, t2ps, t2pb, t2vs, t2vb, polw, dout + 384, VPRE);
  k_mlp<<<128, 64, 0, stream>>>(VPRE, vls, vlb, v1w, v1b, v2w, v2b, v3w, v3b, vfw, vfb, dout);
}

// Round 15
// 1247.556 us; speedup vs baseline: 1.5100x; 1.5100x over previous
//
#include <hip/hip_runtime.h>
#include <cstdint>
#include <cstddef>

typedef _Float16 half_t;
typedef _Float16 h8 __attribute__((ext_vector_type(8)));
typedef _Float16 h4 __attribute__((ext_vector_type(4)));
typedef float f32x4 __attribute__((ext_vector_type(4)));

#define BATCHN 128
#define HWN    225

__device__ __forceinline__ float swishf(float x){ return x / (1.f + __expf(-x)); }

__device__ __forceinline__ void diroff(int d, int o, int& dh, int& dw){
  if (d == 0)      { dh = 0;  dw = o; }
  else if (d == 1) { dh = o;  dw = 0; }
  else if (d == 2) { dh = o;  dw = o; }
  else             { dh = -o; dw = o; }
}

// ---------------- weight conversion fp32 -> fp16 ----------------
__global__ void k_wconv(const float* __restrict__ rbw, const float* __restrict__ rbw2,
                        const float* __restrict__ trw1, const float* __restrict__ trw2,
                        const float* __restrict__ fcw,
                        half_t* __restrict__ W1L, half_t* __restrict__ W2,
                        half_t* __restrict__ TW1, half_t* __restrict__ TW2,
                        half_t* __restrict__ FCW)
{
  int e = blockIdx.x * 256 + threadIdx.x;
  if (e < 786432) {
    int j = e / 196608; int r = e - j * 196608;
    int oc = r / 768;   int k = r - oc * 768;
    int t = k >> 8;     int ic = k & 255;
    W1L[e] = (half_t)rbw[(((size_t)(j*3 + t) * 256 + oc) * 256) + ic];
    return;
  }
  int e2 = e - 786432;
  if (e2 < 262144) { W2[e2] = (half_t)rbw2[e2]; return; }
  int e3 = e2 - 262144;
  if (e3 < 327680) { TW1[e3] = (half_t)trw1[e3]; return; }
  int e4 = e3 - 327680;
  if (e4 < 327680) { TW2[e4] = (half_t)trw2[e4]; return; }
  int e5 = e4 - 327680;
  if (e5 < 32768)  { FCW[e5] = (half_t)fcw[e5]; }
}

// ---------------- fused residual pair, quarter-tiled + copy-free ping-pong ----------------
// R12 structure: 512 threads = 8 waves; wave wv owns output cols wv*32..+31
// (2 col-frags); M in 4 sequential 64-row quarters; acc[4][2] = 32 VGPR.
// GEMM1 barrier-free (B from L2-hot global). Ping-pong prefetch with TWO
// static buffer sets (a0/b0 <-> a1/b1) and explicit ks bodies -> no copies.
// Runtime kc/kt2 loops stay unroll 1 (bounded live set, no scratch).
template<bool LINE>
__device__ __forceinline__ void run_pair(half_t* ylds, half_t* stg,
                                         const half_t* __restrict__ W1p,
                                         const float* __restrict__ b1p,
                                         const half_t* __restrict__ W2p,
                                         const float* __restrict__ b2p,
                                         int d, int wv, int l15, int lq)
{
  constexpr int TAPS = LINE ? 3 : 1;
  constexpr int K1   = LINE ? 768 : 256;

  __syncthreads();   // entry: ylds stable

  float b1v[2], b2v[2];
  #pragma unroll
  for (int nt = 0; nt < 2; ++nt) {
    int col = wv*32 + nt*16 + l15;
    b1v[nt] = b1p[col]; b2v[nt] = b2p[col];
  }
  const half_t* w1r[2];
  const half_t* w2r[2];
  #pragma unroll
  for (int nt = 0; nt < 2; ++nt) {
    int row = wv*32 + nt*16 + l15;
    w1r[nt] = W1p + (size_t)row*K1  + lq*8;
    w2r[nt] = W2p + (size_t)row*256 + lq*8;
  }

  h4 dprev[4][2];   // parked delta of previous quarter (LINE only)

  #pragma unroll 1
  for (int q = 0; q < 4; ++q) {
    // gather row-byte bases for this quarter
    int qb[4][TAPS];
    #pragma unroll
    for (int mt = 0; mt < 4; ++mt) {
      int p = q*64 + mt*16 + l15;
      int pc = (p < 225) ? p : 225;
      if (LINE) {
        int h = pc / 15, w = pc - 15*(pc/15);
        #pragma unroll
        for (int t = 0; t < 3; ++t) {
          int dh, dw; diroff(d, t - 1, dh, dw);
          int h2 = h + dh, w2 = w + dw;
          int qq = (pc < 225 && (unsigned)h2 < 15u && (unsigned)w2 < 15u) ? (h2*15 + w2) : 225;
          qb[mt][t] = qq * 512;
        }
      } else {
        qb[mt][0] = pc * 512;
      }
    }

    f32x4 acc[4][2];
    #pragma unroll
    for (int a = 0; a < 4; ++a)
      #pragma unroll
      for (int b = 0; b < 2; ++b) { f32x4 z = {0.f,0.f,0.f,0.f}; acc[a][b] = z; }

    // ---- GEMM1 copy-free ping-pong: acc = gather(ylds) x W1^T ----
    h8 a0[4], a1[4], b0[2], b1[2];
    {
      const int cb = lq*16;   // (tap=0, kc=0, ks=0)
      #pragma unroll
      for (int mt = 0; mt < 4; ++mt) {
        int rb = qb[mt][0];
        a0[mt] = *(const h8*)((const char*)ylds + rb + (cb ^ ((rb >> 5) & 0x70)));
      }
      #pragma unroll
      for (int nt = 0; nt < 2; ++nt)
        b0[nt] = *(const h8*)(w1r[nt]);
    }
    #pragma unroll
    for (int tap = 0; tap < TAPS; ++tap) {
      #pragma unroll 1
      for (int kc = 0; kc < 4; ++kc) {
        // ks=0: prefetch (tap,kc,1) into buf1, MFMA buf0
        {
          int cb = kc*128 + 64 + lq*16;
          #pragma unroll
          for (int mt = 0; mt < 4; ++mt) {
            int rb = qb[mt][tap];
            a1[mt] = *(const h8*)((const char*)ylds + rb + (cb ^ ((rb >> 5) & 0x70)));
          }
          int ko = (tap*4 + kc)*64 + 32;
          #pragma unroll
          for (int nt = 0; nt < 2; ++nt)
            b1[nt] = *(const h8*)(w1r[nt] + ko);
          #pragma unroll
          for (int nt = 0; nt < 2; ++nt)
            #pragma unroll
            for (int mt = 0; mt < 4; ++mt)
              acc[mt][nt] = __builtin_amdgcn_mfma_f32_16x16x32_f16(a0[mt], b0[nt], acc[mt][nt], 0, 0, 0);
        }
        // ks=1: prefetch next group into buf0 (if any), MFMA buf1
        {
          int tapn = (tap + 1 < TAPS) ? tap + 1 : tap;   // folds after tap unroll
          if (kc < 3) {
            int cb = (kc + 1)*128 + lq*16;
            #pragma unroll
            for (int mt = 0; mt < 4; ++mt) {
              int rb = qb[mt][tap];
              a0[mt] = *(const h8*)((const char*)ylds + rb + (cb ^ ((rb >> 5) & 0x70)));
            }
            int ko = (tap*4 + kc + 1)*64;
            #pragma unroll
            for (int nt = 0; nt < 2; ++nt)
              b0[nt] = *(const h8*)(w1r[nt] + ko);
          } else if (tap + 1 < TAPS) {
            int cb = lq*16;
            #pragma unroll
            for (int mt = 0; mt < 4; ++mt) {
              int rb = qb[mt][tapn];
              a0[mt] = *(const h8*)((const char*)ylds + rb + (cb ^ ((rb >> 5) & 0x70)));
            }
            int ko = (tap + 1)*256;
            #pragma unroll
            for (int nt = 0; nt < 2; ++nt)
              b0[nt] = *(const h8*)(w1r[nt] + ko);
          }
          #pragma unroll
          for (int nt = 0; nt < 2; ++nt)
            #pragma unroll
            for (int mt = 0; mt < 4; ++mt)
              acc[mt][nt] = __builtin_amdgcn_mfma_f32_16x16x32_f16(a1[mt], b1[nt], acc[mt][nt], 0, 0, 0);
        }
      }
    }

    // swish1 -> packed fp16
    h4 s1h[4][2];
    #pragma unroll
    for (int mt = 0; mt < 4; ++mt)
      #pragma unroll
      for (int nt = 0; nt < 2; ++nt)
        #pragma unroll
        for (int r = 0; r < 4; ++r)
          s1h[mt][nt][r] = (half_t)swishf(acc[mt][nt][r] + b1v[nt]);

    __syncthreads();   // A: all GEMM1 gathers of this quarter done; stg reusable

    // apply previous quarter's parked delta (LINE)
    if (LINE && q >= 1) {
      #pragma unroll
      for (int mt = 0; mt < 4; ++mt)
        #pragma unroll
        for (int nt = 0; nt < 2; ++nt)
          #pragma unroll
          for (int r = 0; r < 4; ++r) {
            int p = (q-1)*64 + mt*16 + lq*4 + r;
            if (p < 225) {
              int c = wv*32 + nt*16 + l15;
              half_t* ad = (half_t*)((char*)ylds + p*512 + ((c*2) ^ ((p & 7) << 4)));
              *ad = (half_t)((float)*ad + (float)dprev[mt][nt][r]);
            }
          }
    }

    // stage s1 (64 x 256) into stg
    #pragma unroll
    for (int mt = 0; mt < 4; ++mt)
      #pragma unroll
      for (int nt = 0; nt < 2; ++nt)
        #pragma unroll
        for (int r = 0; r < 4; ++r) {
          int lr = mt*16 + lq*4 + r;
          int cc = wv*32 + nt*16 + l15;
          *(half_t*)((char*)stg + lr*512 + ((cc*2) ^ ((lr & 7) << 4))) = s1h[mt][nt][r];
        }
    __syncthreads();   // B: s1 staged

    // ---- GEMM2 copy-free ping-pong: acc = s1 x W2^T ----
    #pragma unroll
    for (int a = 0; a < 4; ++a)
      #pragma unroll
      for (int b = 0; b < 2; ++b) { f32x4 z = {0.f,0.f,0.f,0.f}; acc[a][b] = z; }

    {
      const int cb0 = lq*16;   // (kt2=0, ks=0)
      #pragma unroll
      for (int mt = 0; mt < 4; ++mt) {
        int lr = mt*16 + l15;
        a0[mt] = *(const h8*)((const char*)stg + lr*512 + (cb0 ^ ((lr & 7) << 4)));
      }
      #pragma unroll
      for (int nt = 0; nt < 2; ++nt)
        b0[nt] = *(const h8*)(w2r[nt]);
    }
    #pragma unroll 1
    for (int kt2 = 0; kt2 < 4; ++kt2) {
      // ks=0: prefetch (kt2,1) into buf1, MFMA buf0
      {
        int cb = kt2*128 + 64 + lq*16;
        #pragma unroll
        for (int mt = 0; mt < 4; ++mt) {
          int lr = mt*16 + l15;
          a1[mt] = *(const h8*)((const char*)stg + lr*512 + (cb ^ ((lr & 7) << 4)));
        }
        int ko = kt2*64 + 32;
        #pragma unroll
        for (int nt = 0; nt < 2; ++nt)
          b1[nt] = *(const h8*)(w2r[nt] + ko);
        #pragma unroll
        for (int nt = 0; nt < 2; ++nt)
          #pragma unroll
          for (int mt = 0; mt < 4; ++mt)
            acc[mt][nt] = __builtin_amdgcn_mfma_f32_16x16x32_f16(a0[mt], b0[nt], acc[mt][nt], 0, 0, 0);
      }
      // ks=1: prefetch (kt2+1,0) into buf0 (if any), MFMA buf1
      {
        if (kt2 < 3) {
          int cb = (kt2 + 1)*128 + lq*16;
          #pragma unroll
          for (int mt = 0; mt < 4; ++mt) {
            int lr = mt*16 + l15;
            a0[mt] = *(const h8*)((const char*)stg + lr*512 + (cb ^ ((lr & 7) << 4)));
          }
          int ko = (kt2 + 1)*64;
          #pragma unroll
          for (int nt = 0; nt < 2; ++nt)
            b0[nt] = *(const h8*)(w2r[nt] + ko);
        }
        #pragma unroll
        for (int nt = 0; nt < 2; ++nt)
          #pragma unroll
          for (int mt = 0; mt < 4; ++mt)
            acc[mt][nt] = __builtin_amdgcn_mfma_f32_16x16x32_f16(a1[mt], b1[nt], acc[mt][nt], 0, 0, 0);
      }
    }

    // ---- epilogue ----
    if (!LINE) {
      #pragma unroll
      for (int mt = 0; mt < 4; ++mt)
        #pragma unroll
        for (int nt = 0; nt < 2; ++nt)
          #pragma unroll
          for (int r = 0; r < 4; ++r) {
            int p = q*64 + mt*16 + lq*4 + r;
            if (p < 225) {
              int c = wv*32 + nt*16 + l15;
              half_t* ad = (half_t*)((char*)ylds + p*512 + ((c*2) ^ ((p & 7) << 4)));
              *ad = (half_t)((float)*ad + swishf(acc[mt][nt][r] + b2v[nt]));
            }
          }
    } else if (q < 3) {
      #pragma unroll
      for (int mt = 0; mt < 4; ++mt)
        #pragma unroll
        for (int nt = 0; nt < 2; ++nt)
          #pragma unroll
          for (int r = 0; r < 4; ++r)
            dprev[mt][nt][r] = (half_t)swishf(acc[mt][nt][r] + b2v[nt]);
    } else {
      #pragma unroll
      for (int mt = 0; mt < 4; ++mt)
        #pragma unroll
        for (int nt = 0; nt < 2; ++nt)
          #pragma unroll
          for (int r = 0; r < 4; ++r) {
            int p = q*64 + mt*16 + lq*4 + r;
            if (p < 225) {
              int c = wv*32 + nt*16 + l15;
              half_t* ad = (half_t*)((char*)ylds + p*512 + ((c*2) ^ ((p & 7) << 4)));
              *ad = (half_t)((float)*ad + swishf(acc[mt][nt][r] + b2v[nt]));
            }
          }
    }
  } // q
}

// ---------------- plane-resident trunk ----------------
// One block per (direction d, image b); 512 threads = 8 waves.
__launch_bounds__(512, 2)
__global__ void k_trunk(const float* __restrict__ x,
                        const float* __restrict__ fw, const float* __restrict__ fb,
                        const half_t* __restrict__ W1L, const float* __restrict__ rbb,
                        const half_t* __restrict__ W2g, const float* __restrict__ rbb2,
                        const half_t* __restrict__ TW1, const float* __restrict__ trb1,
                        const half_t* __restrict__ TW2, const float* __restrict__ trb2,
                        const half_t* __restrict__ FCW, const float* __restrict__ fcb,
                        float* __restrict__ mapf)
{
  __shared__ __align__(16) half_t ylds[226*256];   // 115,712 B
  __shared__ __align__(16) half_t stg[64*256];     //  32,768 B
  const int tid = threadIdx.x;
  const int lane = tid & 63;
  const int wv = tid >> 6;                          // 0..7
  const int l15 = lane & 15, lq = lane >> 4;
  const int pid = blockIdx.x;
  const int d = pid >> 7, bimg = pid & 127;

  // ---- first layer: y = swish(line_conv3(x)) into ylds ----
  {
    float* xl = (float*)stg;                        // 450 floats
    if (tid < 450) xl[tid] = x[(size_t)bimg*450 + tid];
    __syncthreads();
    const int c = tid & 255;
    float fwv0[3], fwv1[3];
    #pragma unroll
    for (int t = 0; t < 3; ++t) {
      fwv0[t] = fw[(t*256 + c)*2 + 0];
      fwv1[t] = fw[(t*256 + c)*2 + 1];
    }
    float fbv = fb[c];
    for (int e = tid; e < 226*256; e += 512) {
      int p = e >> 8;
      float v = 0.f;
      if (p < 225) {
        int h = p / 15, w = p - 15*(p/15);
        float a = fbv;
        #pragma unroll
        for (int t = 0; t < 3; ++t) {
          int dh, dw; diroff(d, t - 1, dh, dw);
          int h2 = h + dh, w2 = w + dw;
          if ((unsigned)h2 < 15u && (unsigned)w2 < 15u)
            a += fwv0[t]*xl[h2*15+w2] + fwv1[t]*xl[225 + h2*15+w2];
        }
        v = swishf(a);
      }
      *(half_t*)((char*)ylds + p*512 + (((e & 255)*2) ^ ((p & 7) << 4))) = (half_t)v;
    }
  }

  // ---- 9 residual pairs ----
  #pragma unroll 1
  for (int j = 0; j < 4; ++j)
    run_pair<true>(ylds, stg, W1L + (size_t)j*196608, rbb + j*256,
                   W2g + (size_t)j*65536, rbb2 + j*256, d, wv, l15, lq);
  #pragma unroll 1
  for (int j = 0; j < 5; ++j)
    run_pair<false>(ylds, stg, TW1 + (size_t)j*65536, trb1 + j*256,
                    TW2 + (size_t)j*65536, trb2 + j*256, d, wv, l15, lq);

  // ---- fc GEMM: mapf = 30*tanh((y x FCW^T + b)/30); wave wv -> cols wv*16..+15 ----
  {
    __syncthreads();   // last epilogue done
    float fbv2 = fcb[wv*16 + l15];
    #pragma unroll 1
    for (int q = 0; q < 4; ++q) {
      int qb0[4];
      #pragma unroll
      for (int mt = 0; mt < 4; ++mt) {
        int p = q*64 + mt*16 + l15;
        qb0[mt] = ((p < 225) ? p : 225) * 512;
      }
      f32x4 acc[4];
      #pragma unroll
      for (int a = 0; a < 4; ++a) { f32x4 z = {0.f,0.f,0.f,0.f}; acc[a] = z; }

      #pragma unroll 1
      for (int kt = 0; kt < 4; ++kt) {
        #pragma unroll
        for (int ks = 0; ks < 2; ++ks) {
          h8 af[4];
          #pragma unroll
          for (int mt = 0; mt < 4; ++mt) {
            int cb = kt*128 + ks*64 + lq*16;
            af[mt] = *(const h8*)((const char*)ylds + qb0[mt] + (cb ^ ((qb0[mt] >> 5) & 0x70)));
          }
          int row = wv*16 + l15;
          h8 bf = *(const h8*)(FCW + (size_t)row*256 + kt*64 + ks*32 + lq*8);
          #pragma unroll
          for (int mt = 0; mt < 4; ++mt)
            acc[mt] = __builtin_amdgcn_mfma_f32_16x16x32_f16(af[mt], bf, acc[mt], 0, 0, 0);
        }
      }
      #pragma unroll
      for (int mt = 0; mt < 4; ++mt)
        #pragma unroll
        for (int r = 0; r < 4; ++r) {
          int p = q*64 + mt*16 + lq*4 + r;
          if (p < 225) {
            int col = wv*16 + l15;
            float v = acc[mt][r] + fbv2;
            mapf[((size_t)((d*BATCHN + bimg)*225 + p))*128 + col] = 30.f * tanhf(v * (1.f/30.f));
          }
        }
    }
  }
}

// ---------------- h1 = prelu(mean_d g1, g1lr_s, bound .999) ----------------
__global__ void k_h1(const float* __restrict__ mapf, const float* __restrict__ g1s,
                     float* __restrict__ h1)
{
  __shared__ float accs[225*65];
  int b = blockIdx.x, tid = threadIdx.x;
  for (int d = 0; d < 4; ++d) {
    for (int e = tid; e < 225*64; e += 256) {
      int hw = e >> 6, c = e & 63;
      float v = mapf[((size_t)(d*BATCHN + b)*225 + hw)*128 + c];
      if (d == 0) accs[hw*65 + c] = v; else accs[hw*65 + c] += v;
    }
  }
  __syncthreads();
  for (int e = tid; e < 225*64; e += 256) {
    int c = e / 225, hw = e - c*225;
    float s = tanhf(g1s[c] * (1.f/0.999f)) * 0.999f;
    float v = accs[hw*65 + c] * 0.25f;
    h1[((size_t)b*64 + c)*225 + hw] = fmaxf(v, s*v);
  }
}

// ---------------- h1c(avg sym) -> h2 -> h3 -> trunk0 ----------------
__global__ void k_h2(const float* __restrict__ h1, const float* __restrict__ mapf,
                     const float* __restrict__ h1w, const float* __restrict__ h1b,
                     const float* __restrict__ s1p, const float* __restrict__ s2p,
                     const float* __restrict__ s3p, const float* __restrict__ b3p,
                     float* __restrict__ tr0)
{
  int bc = blockIdx.x; int b = bc >> 6; int c = bc & 63;
  __shared__ float pl[225];
  int tid = threadIdx.x;
  if (tid < 225) pl[tid] = h1[((size_t)b*64 + c)*225 + tid];
  __syncthreads();
  if (tid >= 225) return;
  int h = tid / 15, w = tid - (tid/15)*15;
  float wk[11];
  #pragma unroll
  for (int i = 0; i < 11; ++i) wk[i] = h1w[i*64 + c];
  float bias = h1b[c];
  float sl1 = tanhf(s1p[c] * (1.f/0.999f)) * 0.999f;
  float sl2 = tanhf(s2p[c] * (1.f/0.999f)) * 0.999f;
  float tsum = 0.f;
  for (int d = 0; d < 4; ++d) {
    float hc = bias;
    #pragma unroll
    for (int i = 0; i < 11; ++i) {
      int dh, dw; diroff(d, i - 5, dh, dw);
      int hp = h + dh, wp = w + dw;
      float vp = ((unsigned)hp < 15u && (unsigned)wp < 15u) ? pl[hp*15 + wp] : 0.f;
      int hm = h - dh, wm = w - dw;
      float vm = ((unsigned)hm < 15u && (unsigned)wm < 15u) ? pl[hm*15 + wm] : 0.f;
      hc += 0.5f * wk[i] * (vp + vm);
    }
    float t = fmaxf(hc, sl1*hc);
    t += mapf[((size_t)(d*BATCHN + b)*225 + tid)*128 + 64 + c];
    t = fmaxf(t, sl2*t);
    tsum += t;
  }
  float h3v = tsum * 0.25f + b3p[c];
  float sl3 = tanhf(s3p[c] * (1.f/0.999f)) * 0.999f;
  tr0[((size_t)b*64 + c)*225 + tid] = fmaxf(h3v, sl3*h3v);
}

// ---------------- shuffle -> grouped 1x1 -> shuffle -> prelu ----------------
__global__ void k_head1(const float* __restrict__ tr0, const float* __restrict__ tc1w,
                        const float* __restrict__ tc1b, const float* __restrict__ tlr1,
                        float* __restrict__ t1o)
{
  __shared__ float st[64*228];
  int b = blockIdx.x, tid = threadIdx.x;
  for (int e = tid; e < 64*225; e += 256) {
    int c = e / 225, hw = e - c*225;
    st[c*228 + hw] = tr0[((size_t)b*64 + c)*225 + hw];
  }
  __syncthreads();
  float s2v[64];
  if (tid < 225) {
    #pragma unroll
    for (int g = 0; g < 16; ++g) {
      int gg = g >> 2, rr = g & 3;
      float x0 = st[(gg*16 + 0*4 + rr)*228 + tid];
      float x1 = st[(gg*16 + 1*4 + rr)*228 + tid];
      float x2 = st[(gg*16 + 2*4 + rr)*228 + tid];
      float x3 = st[(gg*16 + 3*4 + rr)*228 + tid];
      #pragma unroll
      for (int o = 0; o < 4; ++o) {
        s2v[g*4 + o] = tc1b[g*4 + o]
          + x0*tc1w[(g*4 + o)*4 + 0] + x1*tc1w[(g*4 + o)*4 + 1]
          + x2*tc1w[(g*4 + o)*4 + 2] + x3*tc1w[(g*4 + o)*4 + 3];
      }
    }
  }
  __syncthreads();
  if (tid < 225) {
    #pragma unroll
    for (int c = 0; c < 64; ++c) {
      int gg = c >> 4, q = c & 15, ii = q >> 2, jj = q & 3;
      float v = s2v[gg*16 + jj*4 + ii];
      float sl = tanhf(tlr1[c] * (1.f/0.999f)) * 0.999f;
      st[c*228 + tid] = fmaxf(v, sl*v);
    }
  }
  __syncthreads();
  for (int e = tid; e < 64*225; e += 256) {
    int c = e / 225, hw = e - c*225;
    t1o[((size_t)b*64 + c)*225 + hw] = st[c*228 + hw];
  }
}

// ---------------- sym3 depthwise conv + policy head + value pre-pool ----------------
__global__ void k_head2(const float* __restrict__ t1, const float* __restrict__ tc2w,
                        const float* __restrict__ t2ps, const float* __restrict__ t2pb,
                        const float* __restrict__ t2vs, const float* __restrict__ t2vb,
                        const float* __restrict__ polw,
                        float* __restrict__ pout, float* __restrict__ vpre)
{
  __shared__ float st[64*228];
  __shared__ float vbuf[64*228];
  __shared__ float psum[64*4];
  int b = blockIdx.x, tid = threadIdx.x;
  for (int e = tid; e < 64*225; e += 256) {
    int c = e / 225, hw = e - c*225;
    st[c*228 + hw] = t1[((size_t)b*64 + c)*225 + hw];
  }
  __syncthreads();
  if (tid < 225) {
    int h = tid / 15, w = tid - (tid/15)*15;
    float pacc = 0.f;
    for (int c = 0; c < 64; ++c) {
      const float* pc = &st[c*228];
      float ctr = pc[tid];
      float up = (h > 0)  ? pc[tid - 15] : 0.f;
      float dn = (h < 14) ? pc[tid + 15] : 0.f;
      float lf = (w > 0)  ? pc[tid - 1]  : 0.f;
      float rt = (w < 14) ? pc[tid + 1]  : 0.f;
      float ul = (h > 0  && w > 0)  ? pc[tid - 16] : 0.f;
      float ur = (h > 0  && w < 14) ? pc[tid - 14] : 0.f;
      float dl = (h < 14 && w > 0)  ? pc[tid + 14] : 0.f;
      float dr = (h < 14 && w < 14) ? pc[tid + 16] : 0.f;
      float s3 = tc2w[c]*ctr + tc2w[64 + c]*(up + dn + lf + rt)
               + tc2w[128 + c]*(ul + ur + dl + dr);
      float yp = s3 + t2pb[c];
      float sp = tanhf(t2ps[c] * (1.f/0.999f)) * 0.999f;
      pacc += fmaxf(yp, sp*yp) * polw[c];
      float yv = s3 + t2vb[c];
      float sv = tanhf(t2vs[c] * (1.f/0.999f)) * 0.999f;
      vbuf[c*228 + tid] = fmaxf(yv, sv*yv);
    }
    pout[(size_t)b*225 + tid] = pacc;
  }
  __syncthreads();
  {
    int c = tid & 63, q = tid >> 6;
    int h0 = q * 57; int h1e = (h0 + 57 < 225) ? h0 + 57 : 225;
    float s = 0.f;
    for (int hw = h0; hw < h1e; ++hw) s += vbuf[c*228 + hw];
    psum[c*4 + q] = s;
  }
  __syncthreads();
  if (tid < 64) {
    float s = (psum[tid*4] + psum[tid*4+1] + psum[tid*4+2] + psum[tid*4+3]) * (1.f/225.f);
    vpre[(size_t)b*64 + tid] = s;
  }
}

// ---------------- value MLP ----------------
__global__ void k_mlp(const float* __restrict__ vpre, const float* __restrict__ vls,
                      const float* __restrict__ vlb,
                      const float* __restrict__ w1, const float* __restrict__ b1,
                      const float* __restrict__ w2, const float* __restrict__ b2,
                      const float* __restrict__ w3, const float* __restrict__ b3,
                      const float* __restrict__ wf, const float* __restrict__ bfv,
                      float* __restrict__ vout)
{
  __shared__ float va[64], vb2[64];
  int b = blockIdx.x, t = threadIdx.x;
  float x = vpre[(size_t)b*64 + t];
  float s = tanhf(vls[t] * 0.1f) * 10.f;
  float y = x + vlb[t];
  va[t] = fmaxf(y, s*y);
  __syncthreads();
  float acc = b1[t];
  for (int i = 0; i < 64; ++i) acc += w1[t*64 + i] * va[i];
  vb2[t] = fmaxf(acc, 0.f);
  __syncthreads();
  acc = b2[t];
  for (int i = 0; i < 64; ++i) acc += w2[t*64 + i] * vb2[i];
  va[t] = fmaxf(acc, 0.f);
  __syncthreads();
  acc = b3[t];
  for (int i = 0; i < 64; ++i) acc += w3[t*64 + i] * va[i];
  vb2[t] = fmaxf(acc, 0.f);
  __syncthreads();
  if (t < 3) {
    float o = bfv[t];
    for (int i = 0; i < 64; ++i) o += wf[t*64 + i] * vb2[i];
    vout[(size_t)b*3 + t] = o;
  }
}

extern "C" void kernel_launch(void* const* d_in, const int* in_sizes, int n_in,
                              void* d_out, int out_size, void* d_ws, size_t ws_size,
                              hipStream_t stream)
{
  (void)in_sizes; (void)n_in; (void)out_size; (void)ws_size;
  const float* x     = (const float*)d_in[0];
  const float* fw    = (const float*)d_in[1];
  const float* fb    = (const float*)d_in[2];
  const float* rb_w  = (const float*)d_in[3];
  const float* rb_b  = (const float*)d_in[4];
  const float* rb_w2 = (const float*)d_in[5];
  const float* rb_b2 = (const float*)d_in[6];
  const float* tr_w1 = (const float*)d_in[7];
  const float* tr_b1 = (const float*)d_in[8];
  const float* tr_w2 = (const float*)d_in[9];
  const float* tr_b2 = (const float*)d_in[10];
  const float* fc_w  = (const float*)d_in[11];
  const float* fc_b  = (const float*)d_in[12];
  const float* g1lr  = (const float*)d_in[13];
  const float* h1w   = (const float*)d_in[14];
  const float* h1b   = (const float*)d_in[15];
  const float* h1lr1 = (const float*)d_in[16];
  const float* h1lr2 = (const float*)d_in[17];
  const float* h3lr  = (const float*)d_in[18];
  const float* h3lb  = (const float*)d_in[19];
  const float* tc1w  = (const float*)d_in[20];
  const float* tc1b  = (const float*)d_in[21];
  const float* tlr1  = (const float*)d_in[22];
  const float* tc2w  = (const float*)d_in[23];
  const float* t2ps  = (const float*)d_in[24];
  const float* t2pb  = (const float*)d_in[25];
  const float* t2vs  = (const float*)d_in[26];
  const float* t2vb  = (const float*)d_in[27];
  const float* polw  = (const float*)d_in[28];
  const float* vls   = (const float*)d_in[29];
  const float* vlb   = (const float*)d_in[30];
  const float* v1w   = (const float*)d_in[31];
  const float* v1b   = (const float*)d_in[32];
  const float* v2w   = (const float*)d_in[33];
  const float* v2b   = (const float*)d_in[34];
  const float* v3w   = (const float*)d_in[35];
  const float* v3b   = (const float*)d_in[36];
  const float* vfw   = (const float*)d_in[37];
  const float* vfb   = (const float*)d_in[38];

  char* ws = (char*)d_ws;
  size_t off = 0;
  auto alloc = [&](size_t bytes) -> void* {
    void* p = ws + off;
    off += (bytes + 255) & ~(size_t)255;
    return p;
  };
  float* MAPF = (float*)alloc((size_t)4*BATCHN*225*128*4);   // 59 MB
  float* H1   = (float*)alloc((size_t)BATCHN*64*225*4);
  float* TR0  = (float*)alloc((size_t)BATCHN*64*225*4);
  float* T1B  = (float*)alloc((size_t)BATCHN*64*225*4);
  float* VPRE = (float*)alloc((size_t)BATCHN*64*4);
  half_t* W1L = (half_t*)alloc((size_t)4*256*768*2);
  half_t* W2  = (half_t*)alloc((size_t)4*256*256*2);
  half_t* TW1 = (half_t*)alloc((size_t)5*256*256*2);
  half_t* TW2 = (half_t*)alloc((size_t)5*256*256*2);
  half_t* FCW = (half_t*)alloc((size_t)128*256*2);

  k_wconv<<<6784, 256, 0, stream>>>(rb_w, rb_w2, tr_w1, tr_w2, fc_w, W1L, W2, TW1, TW2, FCW);
  k_trunk<<<512, 512, 0, stream>>>(x, fw, fb, W1L, rb_b, W2, rb_b2,
                                   TW1, tr_b1, TW2, tr_b2, FCW, fc_b, MAPF);

  k_h1<<<128, 256, 0, stream>>>(MAPF, g1lr, H1);
  k_h2<<<8192, 256, 0, stream>>>(H1, MAPF, h1w, h1b, h1lr1, h1lr2, h3lr, h3lb, TR0);
  k_head1<<<128, 256, 0, stream>>>(TR0, tc1w, tc1b, tlr1, T1B);
  float* dout = (float*)d_out;
  k_head2<<<128, 256, 0, stream>>>(T1B, tc2w, t2ps, t2pb, t2vs, t2vb, polw, dout + 384, VPRE);
  k_mlp<<<128, 64, 0, stream>>>(VPRE, vls, vlb, v1w, v1b, v2w, v2b, v3w, v3b, vfw, vfb, dout);
}

// Round 16
// 1133.036 us; speedup vs baseline: 1.6626x; 1.1011x over previous
//
#include <hip/hip_runtime.h>
#include <cstdint>
#include <cstddef>

typedef _Float16 half_t;
typedef _Float16 h8 __attribute__((ext_vector_type(8)));
typedef _Float16 h4 __attribute__((ext_vector_type(4)));
typedef float f32x4 __attribute__((ext_vector_type(4)));

#define BATCHN 128
#define HWN    225

// fast swish: x * rcp(1+e^-x)  (v_rcp_f32, ~1ulp; budget-safe vs fp16 storage)
__device__ __forceinline__ float swishf(float x){
  return x * __builtin_amdgcn_rcpf(1.f + __expf(-x));
}
// precise swish for tail kernels (unchanged numerics off critical path)
__device__ __forceinline__ float swishp(float x){ return x / (1.f + __expf(-x)); }

// fast 30*tanh(v/30) = 30 - 60*rcp(e^{v/15}+1); saturates correctly at +-30
__device__ __forceinline__ float tanh30f(float v){
  return 30.f - 60.f * __builtin_amdgcn_rcpf(__expf(v * (1.f/15.f)) + 1.f);
}

__device__ __forceinline__ void diroff(int d, int o, int& dh, int& dw){
  if (d == 0)      { dh = 0;  dw = o; }
  else if (d == 1) { dh = o;  dw = 0; }
  else if (d == 2) { dh = o;  dw = o; }
  else             { dh = -o; dw = o; }
}

// ---------------- weight conversion fp32 -> fp16 ----------------
__global__ void k_wconv(const float* __restrict__ rbw, const float* __restrict__ rbw2,
                        const float* __restrict__ trw1, const float* __restrict__ trw2,
                        const float* __restrict__ fcw,
                        half_t* __restrict__ W1L, half_t* __restrict__ W2,
                        half_t* __restrict__ TW1, half_t* __restrict__ TW2,
                        half_t* __restrict__ FCW)
{
  int e = blockIdx.x * 256 + threadIdx.x;
  if (e < 786432) {
    int j = e / 196608; int r = e - j * 196608;
    int oc = r / 768;   int k = r - oc * 768;
    int t = k >> 8;     int ic = k & 255;
    W1L[e] = (half_t)rbw[(((size_t)(j*3 + t) * 256 + oc) * 256) + ic];
    return;
  }
  int e2 = e - 786432;
  if (e2 < 262144) { W2[e2] = (half_t)rbw2[e2]; return; }
  int e3 = e2 - 262144;
  if (e3 < 327680) { TW1[e3] = (half_t)trw1[e3]; return; }
  int e4 = e3 - 327680;
  if (e4 < 327680) { TW2[e4] = (half_t)trw2[e4]; return; }
  int e5 = e4 - 327680;
  if (e5 < 32768)  { FCW[e5] = (half_t)fcw[e5]; }
}

// ---------------- fused residual pair, quarter-tiled + copy-free ping-pong ----------------
// 512 threads = 8 waves; wave wv owns output cols wv*32..+31 (2 col-frags);
// M in 4 sequential 64-row quarters; acc[4][2] = 32 VGPR.
// GEMM1 barrier-free (B from L2-hot global). Ping-pong prefetch with TWO
// static buffer sets (a0/b0 <-> a1/b1); runtime kc/kt2 loops at unroll 1.
template<bool LINE>
__device__ __forceinline__ void run_pair(half_t* ylds, half_t* stg,
                                         const half_t* __restrict__ W1p,
                                         const float* __restrict__ b1p,
                                         const half_t* __restrict__ W2p,
                                         const float* __restrict__ b2p,
                                         int d, int wv, int l15, int lq)
{
  constexpr int TAPS = LINE ? 3 : 1;
  constexpr int K1   = LINE ? 768 : 256;

  __syncthreads();   // entry: ylds stable

  float b1v[2], b2v[2];
  #pragma unroll
  for (int nt = 0; nt < 2; ++nt) {
    int col = wv*32 + nt*16 + l15;
    b1v[nt] = b1p[col]; b2v[nt] = b2p[col];
  }
  const half_t* w1r[2];
  const half_t* w2r[2];
  #pragma unroll
  for (int nt = 0; nt < 2; ++nt) {
    int row = wv*32 + nt*16 + l15;
    w1r[nt] = W1p + (size_t)row*K1  + lq*8;
    w2r[nt] = W2p + (size_t)row*256 + lq*8;
  }

  h4 dprev[4][2];   // parked delta of previous quarter (LINE only)

  #pragma unroll 1
  for (int q = 0; q < 4; ++q) {
    // gather row-byte bases for this quarter
    int qb[4][TAPS];
    #pragma unroll
    for (int mt = 0; mt < 4; ++mt) {
      int p = q*64 + mt*16 + l15;
      int pc = (p < 225) ? p : 225;
      if (LINE) {
        int h = pc / 15, w = pc - 15*(pc/15);
        #pragma unroll
        for (int t = 0; t < 3; ++t) {
          int dh, dw; diroff(d, t - 1, dh, dw);
          int h2 = h + dh, w2 = w + dw;
          int qq = (pc < 225 && (unsigned)h2 < 15u && (unsigned)w2 < 15u) ? (h2*15 + w2) : 225;
          qb[mt][t] = qq * 512;
        }
      } else {
        qb[mt][0] = pc * 512;
      }
    }

    f32x4 acc[4][2];
    #pragma unroll
    for (int a = 0; a < 4; ++a)
      #pragma unroll
      for (int b = 0; b < 2; ++b) { f32x4 z = {0.f,0.f,0.f,0.f}; acc[a][b] = z; }

    // ---- GEMM1 copy-free ping-pong: acc = gather(ylds) x W1^T ----
    h8 a0[4], a1[4], b0[2], b1[2];
    {
      const int cb = lq*16;   // (tap=0, kc=0, ks=0)
      #pragma unroll
      for (int mt = 0; mt < 4; ++mt) {
        int rb = qb[mt][0];
        a0[mt] = *(const h8*)((const char*)ylds + rb + (cb ^ ((rb >> 5) & 0x70)));
      }
      #pragma unroll
      for (int nt = 0; nt < 2; ++nt)
        b0[nt] = *(const h8*)(w1r[nt]);
    }
    #pragma unroll
    for (int tap = 0; tap < TAPS; ++tap) {
      #pragma unroll 1
      for (int kc = 0; kc < 4; ++kc) {
        // ks=0: prefetch (tap,kc,1) into buf1, MFMA buf0
        {
          int cb = kc*128 + 64 + lq*16;
          #pragma unroll
          for (int mt = 0; mt < 4; ++mt) {
            int rb = qb[mt][tap];
            a1[mt] = *(const h8*)((const char*)ylds + rb + (cb ^ ((rb >> 5) & 0x70)));
          }
          int ko = (tap*4 + kc)*64 + 32;
          #pragma unroll
          for (int nt = 0; nt < 2; ++nt)
            b1[nt] = *(const h8*)(w1r[nt] + ko);
          #pragma unroll
          for (int nt = 0; nt < 2; ++nt)
            #pragma unroll
            for (int mt = 0; mt < 4; ++mt)
              acc[mt][nt] = __builtin_amdgcn_mfma_f32_16x16x32_f16(a0[mt], b0[nt], acc[mt][nt], 0, 0, 0);
        }
        // ks=1: prefetch next group into buf0 (if any), MFMA buf1
        {
          int tapn = (tap + 1 < TAPS) ? tap + 1 : tap;   // folds after tap unroll
          if (kc < 3) {
            int cb = (kc + 1)*128 + lq*16;
            #pragma unroll
            for (int mt = 0; mt < 4; ++mt) {
              int rb = qb[mt][tap];
              a0[mt] = *(const h8*)((const char*)ylds + rb + (cb ^ ((rb >> 5) & 0x70)));
            }
            int ko = (tap*4 + kc + 1)*64;
            #pragma unroll
            for (int nt = 0; nt < 2; ++nt)
              b0[nt] = *(const h8*)(w1r[nt] + ko);
          } else if (tap + 1 < TAPS) {
            int cb = lq*16;
            #pragma unroll
            for (int mt = 0; mt < 4; ++mt) {
              int rb = qb[mt][tapn];
              a0[mt] = *(const h8*)((const char*)ylds + rb + (cb ^ ((rb >> 5) & 0x70)));
            }
            int ko = (tap + 1)*256;
            #pragma unroll
            for (int nt = 0; nt < 2; ++nt)
              b0[nt] = *(const h8*)(w1r[nt] + ko);
          }
          #pragma unroll
          for (int nt = 0; nt < 2; ++nt)
            #pragma unroll
            for (int mt = 0; mt < 4; ++mt)
              acc[mt][nt] = __builtin_amdgcn_mfma_f32_16x16x32_f16(a1[mt], b1[nt], acc[mt][nt], 0, 0, 0);
        }
      }
    }

    // swish1 -> packed fp16
    h4 s1h[4][2];
    #pragma unroll
    for (int mt = 0; mt < 4; ++mt)
      #pragma unroll
      for (int nt = 0; nt < 2; ++nt)
        #pragma unroll
        for (int r = 0; r < 4; ++r)
          s1h[mt][nt][r] = (half_t)swishf(acc[mt][nt][r] + b1v[nt]);

    __syncthreads();   // A: all GEMM1 gathers of this quarter done; stg reusable

    // apply previous quarter's parked delta (LINE)
    if (LINE && q >= 1) {
      #pragma unroll
      for (int mt = 0; mt < 4; ++mt)
        #pragma unroll
        for (int nt = 0; nt < 2; ++nt)
          #pragma unroll
          for (int r = 0; r < 4; ++r) {
            int p = (q-1)*64 + mt*16 + lq*4 + r;
            if (p < 225) {
              int c = wv*32 + nt*16 + l15;
              half_t* ad = (half_t*)((char*)ylds + p*512 + ((c*2) ^ ((p & 7) << 4)));
              *ad = (half_t)((float)*ad + (float)dprev[mt][nt][r]);
            }
          }
    }

    // stage s1 (64 x 256) into stg
    #pragma unroll
    for (int mt = 0; mt < 4; ++mt)
      #pragma unroll
      for (int nt = 0; nt < 2; ++nt)
        #pragma unroll
        for (int r = 0; r < 4; ++r) {
          int lr = mt*16 + lq*4 + r;
          int cc = wv*32 + nt*16 + l15;
          *(half_t*)((char*)stg + lr*512 + ((cc*2) ^ ((lr & 7) << 4))) = s1h[mt][nt][r];
        }
    __syncthreads();   // B: s1 staged

    // ---- GEMM2 copy-free ping-pong: acc = s1 x W2^T ----
    #pragma unroll
    for (int a = 0; a < 4; ++a)
      #pragma unroll
      for (int b = 0; b < 2; ++b) { f32x4 z = {0.f,0.f,0.f,0.f}; acc[a][b] = z; }

    {
      const int cb0 = lq*16;   // (kt2=0, ks=0)
      #pragma unroll
      for (int mt = 0; mt < 4; ++mt) {
        int lr = mt*16 + l15;
        a0[mt] = *(const h8*)((const char*)stg + lr*512 + (cb0 ^ ((lr & 7) << 4)));
      }
      #pragma unroll
      for (int nt = 0; nt < 2; ++nt)
        b0[nt] = *(const h8*)(w2r[nt]);
    }
    #pragma unroll 1
    for (int kt2 = 0; kt2 < 4; ++kt2) {
      // ks=0: prefetch (kt2,1) into buf1, MFMA buf0
      {
        int cb = kt2*128 + 64 + lq*16;
        #pragma unroll
        for (int mt = 0; mt < 4; ++mt) {
          int lr = mt*16 + l15;
          a1[mt] = *(const h8*)((const char*)stg + lr*512 + (cb ^ ((lr & 7) << 4)));
        }
        int ko = kt2*64 + 32;
        #pragma unroll
        for (int nt = 0; nt < 2; ++nt)
          b1[nt] = *(const h8*)(w2r[nt] + ko);
        #pragma unroll
        for (int nt = 0; nt < 2; ++nt)
          #pragma unroll
          for (int mt = 0; mt < 4; ++mt)
            acc[mt][nt] = __builtin_amdgcn_mfma_f32_16x16x32_f16(a0[mt], b0[nt], acc[mt][nt], 0, 0, 0);
      }
      // ks=1: prefetch (kt2+1,0) into buf0 (if any), MFMA buf1
      {
        if (kt2 < 3) {
          int cb = (kt2 + 1)*128 + lq*16;
          #pragma unroll
          for (int mt = 0; mt < 4; ++mt) {
            int lr = mt*16 + l15;
            a0[mt] = *(const h8*)((const char*)stg + lr*512 + (cb ^ ((lr & 7) << 4)));
          }
          int ko = (kt2 + 1)*64;
          #pragma unroll
          for (int nt = 0; nt < 2; ++nt)
            b0[nt] = *(const h8*)(w2r[nt] + ko);
        }
        #pragma unroll
        for (int nt = 0; nt < 2; ++nt)
          #pragma unroll
          for (int mt = 0; mt < 4; ++mt)
            acc[mt][nt] = __builtin_amdgcn_mfma_f32_16x16x32_f16(a1[mt], b1[nt], acc[mt][nt], 0, 0, 0);
      }
    }

    // ---- epilogue ----
    if (!LINE) {
      #pragma unroll
      for (int mt = 0; mt < 4; ++mt)
        #pragma unroll
        for (int nt = 0; nt < 2; ++nt)
          #pragma unroll
          for (int r = 0; r < 4; ++r) {
            int p = q*64 + mt*16 + lq*4 + r;
            if (p < 225) {
              int c = wv*32 + nt*16 + l15;
              half_t* ad = (half_t*)((char*)ylds + p*512 + ((c*2) ^ ((p & 7) << 4)));
              *ad = (half_t)((float)*ad + swishf(acc[mt][nt][r] + b2v[nt]));
            }
          }
    } else if (q < 3) {
      #pragma unroll
      for (int mt = 0; mt < 4; ++mt)
        #pragma unroll
        for (int nt = 0; nt < 2; ++nt)
          #pragma unroll
          for (int r = 0; r < 4; ++r)
            dprev[mt][nt][r] = (half_t)swishf(acc[mt][nt][r] + b2v[nt]);
    } else {
      #pragma unroll
      for (int mt = 0; mt < 4; ++mt)
        #pragma unroll
        for (int nt = 0; nt < 2; ++nt)
          #pragma unroll
          for (int r = 0; r < 4; ++r) {
            int p = q*64 + mt*16 + lq*4 + r;
            if (p < 225) {
              int c = wv*32 + nt*16 + l15;
              half_t* ad = (half_t*)((char*)ylds + p*512 + ((c*2) ^ ((p & 7) << 4)));
              *ad = (half_t)((float)*ad + swishf(acc[mt][nt][r] + b2v[nt]));
            }
          }
    }
  } // q
}

// ---------------- plane-resident trunk ----------------
__launch_bounds__(512, 2)
__global__ void k_trunk(const float* __restrict__ x,
                        const float* __restrict__ fw, const float* __restrict__ fb,
                        const half_t* __restrict__ W1L, const float* __restrict__ rbb,
                        const half_t* __restrict__ W2g, const float* __restrict__ rbb2,
                        const half_t* __restrict__ TW1, const float* __restrict__ trb1,
                        const half_t* __restrict__ TW2, const float* __restrict__ trb2,
                        const half_t* __restrict__ FCW, const float* __restrict__ fcb,
                        float* __restrict__ mapf)
{
  __shared__ __align__(16) half_t ylds[226*256];   // 115,712 B
  __shared__ __align__(16) half_t stg[64*256];     //  32,768 B
  const int tid = threadIdx.x;
  const int lane = tid & 63;
  const int wv = tid >> 6;                          // 0..7
  const int l15 = lane & 15, lq = lane >> 4;
  const int pid = blockIdx.x;
  const int d = pid >> 7, bimg = pid & 127;

  // ---- first layer: y = swish(line_conv3(x)) into ylds ----
  {
    float* xl = (float*)stg;                        // 450 floats
    if (tid < 450) xl[tid] = x[(size_t)bimg*450 + tid];
    __syncthreads();
    const int c = tid & 255;
    float fwv0[3], fwv1[3];
    #pragma unroll
    for (int t = 0; t < 3; ++t) {
      fwv0[t] = fw[(t*256 + c)*2 + 0];
      fwv1[t] = fw[(t*256 + c)*2 + 1];
    }
    float fbv = fb[c];
    for (int e = tid; e < 226*256; e += 512) {
      int p = e >> 8;
      float v = 0.f;
      if (p < 225) {
        int h = p / 15, w = p - 15*(p/15);
        float a = fbv;
        #pragma unroll
        for (int t = 0; t < 3; ++t) {
          int dh, dw; diroff(d, t - 1, dh, dw);
          int h2 = h + dh, w2 = w + dw;
          if ((unsigned)h2 < 15u && (unsigned)w2 < 15u)
            a += fwv0[t]*xl[h2*15+w2] + fwv1[t]*xl[225 + h2*15+w2];
        }
        v = swishf(a);
      }
      *(half_t*)((char*)ylds + p*512 + (((e & 255)*2) ^ ((p & 7) << 4))) = (half_t)v;
    }
  }

  // ---- 9 residual pairs ----
  #pragma unroll 1
  for (int j = 0; j < 4; ++j)
    run_pair<true>(ylds, stg, W1L + (size_t)j*196608, rbb + j*256,
                   W2g + (size_t)j*65536, rbb2 + j*256, d, wv, l15, lq);
  #pragma unroll 1
  for (int j = 0; j < 5; ++j)
    run_pair<false>(ylds, stg, TW1 + (size_t)j*65536, trb1 + j*256,
                    TW2 + (size_t)j*65536, trb2 + j*256, d, wv, l15, lq);

  // ---- fc GEMM: mapf = 30*tanh((y x FCW^T + b)/30); wave wv -> cols wv*16..+15 ----
  {
    __syncthreads();   // last epilogue done
    float fbv2 = fcb[wv*16 + l15];
    #pragma unroll 1
    for (int q = 0; q < 4; ++q) {
      int qb0[4];
      #pragma unroll
      for (int mt = 0; mt < 4; ++mt) {
        int p = q*64 + mt*16 + l15;
        qb0[mt] = ((p < 225) ? p : 225) * 512;
      }
      f32x4 acc[4];
      #pragma unroll
      for (int a = 0; a < 4; ++a) { f32x4 z = {0.f,0.f,0.f,0.f}; acc[a] = z; }

      #pragma unroll 1
      for (int kt = 0; kt < 4; ++kt) {
        #pragma unroll
        for (int ks = 0; ks < 2; ++ks) {
          h8 af[4];
          #pragma unroll
          for (int mt = 0; mt < 4; ++mt) {
            int cb = kt*128 + ks*64 + lq*16;
            af[mt] = *(const h8*)((const char*)ylds + qb0[mt] + (cb ^ ((qb0[mt] >> 5) & 0x70)));
          }
          int row = wv*16 + l15;
          h8 bf = *(const h8*)(FCW + (size_t)row*256 + kt*64 + ks*32 + lq*8);
          #pragma unroll
          for (int mt = 0; mt < 4; ++mt)
            acc[mt] = __builtin_amdgcn_mfma_f32_16x16x32_f16(af[mt], bf, acc[mt], 0, 0, 0);
        }
      }
      #pragma unroll
      for (int mt = 0; mt < 4; ++mt)
        #pragma unroll
        for (int r = 0; r < 4; ++r) {
          int p = q*64 + mt*16 + lq*4 + r;
          if (p < 225) {
            int col = wv*16 + l15;
            float v = acc[mt][r] + fbv2;
            mapf[((size_t)((d*BATCHN + bimg)*225 + p))*128 + col] = tanh30f(v);
          }
        }
    }
  }
}

// ---------------- h1 = prelu(mean_d g1, g1lr_s, bound .999) ----------------
__global__ void k_h1(const float* __restrict__ mapf, const float* __restrict__ g1s,
                     float* __restrict__ h1)
{
  __shared__ float accs[225*65];
  int b = blockIdx.x, tid = threadIdx.x;
  for (int d = 0; d < 4; ++d) {
    for (int e = tid; e < 225*64; e += 256) {
      int hw = e >> 6, c = e & 63;
      float v = mapf[((size_t)(d*BATCHN + b)*225 + hw)*128 + c];
      if (d == 0) accs[hw*65 + c] = v; else accs[hw*65 + c] += v;
    }
  }
  __syncthreads();
  for (int e = tid; e < 225*64; e += 256) {
    int c = e / 225, hw = e - c*225;
    float s = tanhf(g1s[c] * (1.f/0.999f)) * 0.999f;
    float v = accs[hw*65 + c] * 0.25f;
    h1[((size_t)b*64 + c)*225 + hw] = fmaxf(v, s*v);
  }
}

// ---------------- h1c(avg sym) -> h2 -> h3 -> trunk0 ----------------
__global__ void k_h2(const float* __restrict__ h1, const float* __restrict__ mapf,
                     const float* __restrict__ h1w, const float* __restrict__ h1b,
                     const float* __restrict__ s1p, const float* __restrict__ s2p,
                     const float* __restrict__ s3p, const float* __restrict__ b3p,
                     float* __restrict__ tr0)
{
  int bc = blockIdx.x; int b = bc >> 6; int c = bc & 63;
  __shared__ float pl[225];
  int tid = threadIdx.x;
  if (tid < 225) pl[tid] = h1[((size_t)b*64 + c)*225 + tid];
  __syncthreads();
  if (tid >= 225) return;
  int h = tid / 15, w = tid - (tid/15)*15;
  float wk[11];
  #pragma unroll
  for (int i = 0; i < 11; ++i) wk[i] = h1w[i*64 + c];
  float bias = h1b[c];
  float sl1 = tanhf(s1p[c] * (1.f/0.999f)) * 0.999f;
  float sl2 = tanhf(s2p[c] * (1.f/0.999f)) * 0.999f;
  float tsum = 0.f;
  for (int d = 0; d < 4; ++d) {
    float hc = bias;
    #pragma unroll
    for (int i = 0; i < 11; ++i) {
      int dh, dw; diroff(d, i - 5, dh, dw);
      int hp = h + dh, wp = w + dw;
      float vp = ((unsigned)hp < 15u && (unsigned)wp < 15u) ? pl[hp*15 + wp] : 0.f;
      int hm = h - dh, wm = w - dw;
      float vm = ((unsigned)hm < 15u && (unsigned)wm < 15u) ? pl[hm*15 + wm] : 0.f;
      hc += 0.5f * wk[i] * (vp + vm);
    }
    float t = fmaxf(hc, sl1*hc);
    t += mapf[((size_t)(d*BATCHN + b)*225 + tid)*128 + 64 + c];
    t = fmaxf(t, sl2*t);
    tsum += t;
  }
  float h3v = tsum * 0.25f + b3p[c];
  float sl3 = tanhf(s3p[c] * (1.f/0.999f)) * 0.999f;
  tr0[((size_t)b*64 + c)*225 + tid] = fmaxf(h3v, sl3*h3v);
}

// ---------------- shuffle -> grouped 1x1 -> shuffle -> prelu ----------------
__global__ void k_head1(const float* __restrict__ tr0, const float* __restrict__ tc1w,
                        const float* __restrict__ tc1b, const float* __restrict__ tlr1,
                        float* __restrict__ t1o)
{
  __shared__ float st[64*228];
  int b = blockIdx.x, tid = threadIdx.x;
  for (int e = tid; e < 64*225; e += 256) {
    int c = e / 225, hw = e - c*225;
    st[c*228 + hw] = tr0[((size_t)b*64 + c)*225 + hw];
  }
  __syncthreads();
  float s2v[64];
  if (tid < 225) {
    #pragma unroll
    for (int g = 0; g < 16; ++g) {
      int gg = g >> 2, rr = g & 3;
      float x0 = st[(gg*16 + 0*4 + rr)*228 + tid];
      float x1 = st[(gg*16 + 1*4 + rr)*228 + tid];
      float x2 = st[(gg*16 + 2*4 + rr)*228 + tid];
      float x3 = st[(gg*16 + 3*4 + rr)*228 + tid];
      #pragma unroll
      for (int o = 0; o < 4; ++o) {
        s2v[g*4 + o] = tc1b[g*4 + o]
          + x0*tc1w[(g*4 + o)*4 + 0] + x1*tc1w[(g*4 + o)*4 + 1]
          + x2*tc1w[(g*4 + o)*4 + 2] + x3*tc1w[(g*4 + o)*4 + 3];
      }
    }
  }
  __syncthreads();
  if (tid < 225) {
    #pragma unroll
    for (int c = 0; c < 64; ++c) {
      int gg = c >> 4, q = c & 15, ii = q >> 2, jj = q & 3;
      float v = s2v[gg*16 + jj*4 + ii];
      float sl = tanhf(tlr1[c] * (1.f/0.999f)) * 0.999f;
      st[c*228 + tid] = fmaxf(v, sl*v);
    }
  }
  __syncthreads();
  for (int e = tid; e < 64*225; e += 256) {
    int c = e / 225, hw = e - c*225;
    t1o[((size_t)b*64 + c)*225 + hw] = st[c*228 + hw];
  }
}

// ---------------- sym3 depthwise conv + policy head + value pre-pool ----------------
__global__ void k_head2(const float* __restrict__ t1, const float* __restrict__ tc2w,
                        const float* __restrict__ t2ps, const float* __restrict__ t2pb,
                        const float* __restrict__ t2vs, const float* __restrict__ t2vb,
                        const float* __restrict__ polw,
                        float* __restrict__ pout, float* __restrict__ vpre)
{
  __shared__ float st[64*228];
  __shared__ float vbuf[64*228];
  __shared__ float psum[64*4];
  int b = blockIdx.x, tid = threadIdx.x;
  for (int e = tid; e < 64*225; e += 256) {
    int c = e / 225, hw = e - c*225;
    st[c*228 + hw] = t1[((size_t)b*64 + c)*225 + hw];
  }
  __syncthreads();
  if (tid < 225) {
    int h = tid / 15, w = tid - (tid/15)*15;
    float pacc = 0.f;
    for (int c = 0; c < 64; ++c) {
      const float* pc = &st[c*228];
      float ctr = pc[tid];
      float up = (h > 0)  ? pc[tid - 15] : 0.f;
      float dn = (h < 14) ? pc[tid + 15] : 0.f;
      float lf = (w > 0)  ? pc[tid - 1]  : 0.f;
      float rt = (w < 14) ? pc[tid + 1]  : 0.f;
      float ul = (h > 0  && w > 0)  ? pc[tid - 16] : 0.f;
      float ur = (h > 0  && w < 14) ? pc[tid - 14] : 0.f;
      float dl = (h < 14 && w > 0)  ? pc[tid + 14] : 0.f;
      float dr = (h < 14 && w < 14) ? pc[tid + 16] : 0.f;
      float s3 = tc2w[c]*ctr + tc2w[64 + c]*(up + dn + lf + rt)
               + tc2w[128 + c]*(ul + ur + dl + dr);
      float yp = s3 + t2pb[c];
      float sp = tanhf(t2ps[c] * (1.f/0.999f)) * 0.999f;
      pacc += fmaxf(yp, sp*yp) * polw[c];
      float yv = s3 + t2vb[c];
      float sv = tanhf(t2vs[c] * (1.f/0.999f)) * 0.999f;
      vbuf[c*228 + tid] = fmaxf(yv, sv*yv);
    }
    pout[(size_t)b*225 + tid] = pacc;
  }
  __syncthreads();
  {
    int c = tid & 63, q = tid >> 6;
    int h0 = q * 57; int h1e = (h0 + 57 < 225) ? h0 + 57 : 225;
    float s = 0.f;
    for (int hw = h0; hw < h1e; ++hw) s += vbuf[c*228 + hw];
    psum[c*4 + q] = s;
  }
  __syncthreads();
  if (tid < 64) {
    float s = (psum[tid*4] + psum[tid*4+1] + psum[tid*4+2] + psum[tid*4+3]) * (1.f/225.f);
    vpre[(size_t)b*64 + tid] = s;
  }
}

// ---------------- value MLP ----------------
__global__ void k_mlp(const float* __restrict__ vpre, const float* __restrict__ vls,
                      const float* __restrict__ vlb,
                      const float* __restrict__ w1, const float* __restrict__ b1,
                      const float* __restrict__ w2, const float* __restrict__ b2,
                      const float* __restrict__ w3, const float* __restrict__ b3,
                      const float* __restrict__ wf, const float* __restrict__ bfv,
                      float* __restrict__ vout)
{
  __shared__ float va[64], vb2[64];
  int b = blockIdx.x, t = threadIdx.x;
  float x = vpre[(size_t)b*64 + t];
  float s = tanhf(vls[t] * 0.1f) * 10.f;
  float y = x + vlb[t];
  va[t] = fmaxf(y, s*y);
  __syncthreads();
  float acc = b1[t];
  for (int i = 0; i < 64; ++i) acc += w1[t*64 + i] * va[i];
  vb2[t] = fmaxf(acc, 0.f);
  __syncthreads();
  acc = b2[t];
  for (int i = 0; i < 64; ++i) acc += w2[t*64 + i] * vb2[i];
  va[t] = fmaxf(acc, 0.f);
  __syncthreads();
  acc = b3[t];
  for (int i = 0; i < 64; ++i) acc += w3[t*64 + i] * va[i];
  vb2[t] = fmaxf(acc, 0.f);
  __syncthreads();
  if (t < 3) {
    float o = bfv[t];
    for (int i = 0; i < 64; ++i) o += wf[t*64 + i] * vb2[i];
    vout[(size_t)b*3 + t] = o;
  }
}

extern "C" void kernel_launch(void* const* d_in, const int* in_sizes, int n_in,
                              void* d_out, int out_size, void* d_ws, size_t ws_size,
                              hipStream_t stream)
{
  (void)in_sizes; (void)n_in; (void)out_size; (void)ws_size;
  const float* x     = (const float*)d_in[0];
  const float* fw    = (const float*)d_in[1];
  const float* fb    = (const float*)d_in[2];
  const float* rb_w  = (const float*)d_in[3];
  const float* rb_b  = (const float*)d_in[4];
  const float* rb_w2 = (const float*)d_in[5];
  const float* rb_b2 = (const float*)d_in[6];
  const float* tr_w1 = (const float*)d_in[7];
  const float* tr_b1 = (const float*)d_in[8];
  const float* tr_w2 = (const float*)d_in[9];
  const float* tr_b2 = (const float*)d_in[10];
  const float* fc_w  = (const float*)d_in[11];
  const float* fc_b  = (const float*)d_in[12];
  const float* g1lr  = (const float*)d_in[13];
  const float* h1w   = (const float*)d_in[14];
  const float* h1b   = (const float*)d_in[15];
  const float* h1lr1 = (const float*)d_in[16];
  const float* h1lr2 = (const float*)d_in[17];
  const float* h3lr  = (const float*)d_in[18];
  const float* h3lb  = (const float*)d_in[19];
  const float* tc1w  = (const float*)d_in[20];
  const float* tc1b  = (const float*)d_in[21];
  const float* tlr1  = (const float*)d_in[22];
  const float* tc2w  = (const float*)d_in[23];
  const float* t2ps  = (const float*)d_in[24];
  const float* t2pb  = (const float*)d_in[25];
  const float* t2vs  = (const float*)d_in[26];
  const float* t2vb  = (const float*)d_in[27];
  const float* polw  = (const float*)d_in[28];
  const float* vls   = (const float*)d_in[29];
  const float* vlb   = (const float*)d_in[30];
  const float* v1w   = (const float*)d_in[31];
  const float* v1b   = (const float*)d_in[32];
  const float* v2w   = (const float*)d_in[33];
  const float* v2b   = (const float*)d_in[34];
  const float* v3w   = (const float*)d_in[35];
  const float* v3b   = (const float*)d_in[36];
  const float* vfw   = (const float*)d_in[37];
  const float* vfb   = (const float*)d_in[38];

  char* ws = (char*)d_ws;
  size_t off = 0;
  auto alloc = [&](size_t bytes) -> void* {
    void* p = ws + off;
    off += (bytes + 255) & ~(size_t)255;
    return p;
  };
  float* MAPF = (float*)alloc((size_t)4*BATCHN*225*128*4);   // 59 MB
  float* H1   = (float*)alloc((size_t)BATCHN*64*225*4);
  float* TR0  = (float*)alloc((size_t)BATCHN*64*225*4);
  float* T1B  = (float*)alloc((size_t)BATCHN*64*225*4);
  float* VPRE = (float*)alloc((size_t)BATCHN*64*4);
  half_t* W1L = (half_t*)alloc((size_t)4*256*768*2);
  half_t* W2  = (half_t*)alloc((size_t)4*256*256*2);
  half_t* TW1 = (half_t*)alloc((size_t)5*256*256*2);
  half_t* TW2 = (half_t*)alloc((size_t)5*256*256*2);
  half_t* FCW = (half_t*)alloc((size_t)128*256*2);

  k_wconv<<<6784, 256, 0, stream>>>(rb_w, rb_w2, tr_w1, tr_w2, fc_w, W1L, W2, TW1, TW2, FCW);
  k_trunk<<<512, 512, 0, stream>>>(x, fw, fb, W1L, rb_b, W2, rb_b2,
                                   TW1, tr_b1, TW2, tr_b2, FCW, fc_b, MAPF);

  k_h1<<<128, 256, 0, stream>>>(MAPF, g1lr, H1);
  k_h2<<<8192, 256, 0, stream>>>(H1, MAPF, h1w, h1b, h1lr1, h1lr2, h3lr, h3lb, TR0);
  k_head1<<<128, 256, 0, stream>>>(TR0, tc1w, tc1b, tlr1, T1B);
  float* dout = (float*)d_out;
  k_head2<<<128, 256, 0, stream>>>(T1B, tc2w, t2ps, t2pb, t2vs, t2vb, polw, dout + 384, VPRE);
  k_mlp<<<128, 64, 0, stream>>>(VPRE, vls, vlb, v1w, v1b, v2w, v2b, v3w, v3b, vfw, vfb, dout);
}